// Round 1
// baseline (160.415 us; speedup 1.0000x reference)
//
#include <hip/hip_runtime.h>
#include <math.h>

#define EPSV 1e-5f
#define HW   4096     // H*W = 64*64
#define NBC  16384    // B*C = 64*256

// ---------------- Pass 1: per-channel stats + MLPs -> affine coefs ----------
__global__ __launch_bounds__(256) void cnsn_stats(
    const float* __restrict__ x,
    const float* __restrict__ wm1, const float* __restrict__ bm1,
    const float* __restrict__ wm2, const float* __restrict__ bm2,
    const float* __restrict__ ws1, const float* __restrict__ bs1,
    const float* __restrict__ ws2, const float* __restrict__ bs2,
    float* __restrict__ coefA, float* __restrict__ coefB)
{
    const int bc = blockIdx.x;                 // 0..NBC-1
    const float4* xp4 = (const float4*)(x + (size_t)bc * HW);
    const int tid = threadIdx.x;

    float sum = 0.f, sumsq = 0.f;
    // 4096 floats / 256 threads = 16 floats = 4 float4 per thread
    #pragma unroll
    for (int it = 0; it < 4; ++it) {
        float4 v = xp4[tid + it * 256];
        sum   += v.x + v.y + v.z + v.w;
        sumsq += v.x*v.x + v.y*v.y + v.z*v.z + v.w*v.w;
    }
    // wave(64) butterfly reduce
    #pragma unroll
    for (int off = 32; off > 0; off >>= 1) {
        sum   += __shfl_down(sum,   off, 64);
        sumsq += __shfl_down(sumsq, off, 64);
    }
    __shared__ float s_sum[4], s_sq[4];
    const int wave = tid >> 6;
    if ((tid & 63) == 0) { s_sum[wave] = sum; s_sq[wave] = sumsq; }
    __syncthreads();

    if (tid == 0) {
        const float S = s_sum[0] + s_sum[1] + s_sum[2] + s_sum[3];
        const float Q = s_sq[0]  + s_sq[1]  + s_sq[2]  + s_sq[3];
        const float N = (float)HW;
        const float mean = S / N;
        const float var  = (Q - S * mean) / (N - 1.0f);   // ddof=1
        const float stdv = sqrtf(var + EPSV);

        // MLP for mean_w: 2 -> 16 (relu) -> 1 (sigmoid)
        float accm = bm2[0];
        #pragma unroll
        for (int h = 0; h < 16; ++h) {
            float hv = fmaf(wm1[h*2+0], mean, fmaf(wm1[h*2+1], stdv, bm1[h]));
            accm = fmaf(wm2[h], fmaxf(hv, 0.f), accm);
        }
        const float mw = 1.f / (1.f + expf(-accm));

        // MLP for std_w
        float accs = bs2[0];
        #pragma unroll
        for (int h = 0; h < 16; ++h) {
            float hv = fmaf(ws1[h*2+0], mean, fmaf(ws1[h*2+1], stdv, bs1[h]));
            accs = fmaf(ws2[h], fmaxf(hv, 0.f), accs);
        }
        const float sw = 1.f / (1.f + expf(-accs));

        // out = (x - m)*sw + m*mw = sw*x + m*(mw - sw)
        coefA[bc] = sw;
        coefB[bc] = mean * (mw - sw);
    }
}

// ---------------- Pass 2: out = A[bc]*x + B[bc] (float4) --------------------
__global__ __launch_bounds__(256) void cnsn_apply(
    const float* __restrict__ x,
    const float* __restrict__ coefA, const float* __restrict__ coefB,
    float* __restrict__ out, int n4)
{
    const int stride = gridDim.x * blockDim.x;
    for (int i = blockIdx.x * blockDim.x + threadIdx.x; i < n4; i += stride) {
        const int bc = i >> 10;                 // 4096 elems / 4 per float4
        const float a = coefA[bc];
        const float b = coefB[bc];
        float4 v = ((const float4*)x)[i];
        float4 o;
        o.x = fmaf(v.x, a, b);
        o.y = fmaf(v.y, a, b);
        o.z = fmaf(v.z, a, b);
        o.w = fmaf(v.w, a, b);
        ((float4*)out)[i] = o;
    }
}

extern "C" void kernel_launch(void* const* d_in, const int* in_sizes, int n_in,
                              void* d_out, int out_size, void* d_ws, size_t ws_size,
                              hipStream_t stream) {
    const float* x   = (const float*)d_in[0];
    const float* wm1 = (const float*)d_in[1];
    const float* bm1 = (const float*)d_in[2];
    const float* wm2 = (const float*)d_in[3];
    const float* bm2 = (const float*)d_in[4];
    const float* ws1 = (const float*)d_in[5];
    const float* bs1 = (const float*)d_in[6];
    const float* ws2 = (const float*)d_in[7];
    const float* bs2 = (const float*)d_in[8];
    float* out = (float*)d_out;

    float* coefA = (float*)d_ws;           // NBC floats
    float* coefB = coefA + NBC;            // NBC floats  (128 KiB total)

    cnsn_stats<<<NBC, 256, 0, stream>>>(x, wm1, bm1, wm2, bm2,
                                        ws1, bs1, ws2, bs2, coefA, coefB);

    const int n4 = out_size / 4;           // 16,777,216 float4s
    const int blocks = 2048;               // 256 CU * 8 blocks, grid-stride
    cnsn_apply<<<blocks, 256, 0, stream>>>(x, coefA, coefB, out, n4);
}

// Round 2
// 100.324 us; speedup vs baseline: 1.5990x; 1.5990x over previous
//
#include <hip/hip_runtime.h>
#include <math.h>

#define EPSV 1e-5f
#define HW   4096     // H*W = 64*64
#define NBC  16384    // B*C = 64*256

// Fused: per-channel stats + MLPs + affine apply, x held in registers.
// One 256-thread block per (b,c) channel; 16 floats/thread.
__global__ __launch_bounds__(256) void cnsn_fused(
    const float* __restrict__ x,
    const float* __restrict__ wm1, const float* __restrict__ bm1,
    const float* __restrict__ wm2, const float* __restrict__ bm2,
    const float* __restrict__ ws1, const float* __restrict__ bs1,
    const float* __restrict__ ws2, const float* __restrict__ bs2,
    float* __restrict__ out)
{
    const int bc = blockIdx.x;                 // 0..NBC-1
    const size_t base = (size_t)bc * HW;
    const float4* __restrict__ xp4 = (const float4*)(x + base);
    float4*       __restrict__ op4 = (float4*)(out + base);
    const int tid = threadIdx.x;

    // ---- load 4 x float4 into registers, accumulate sum / sumsq ----
    float4 v[4];
    float sum = 0.f, sumsq = 0.f;
    #pragma unroll
    for (int it = 0; it < 4; ++it) {
        v[it] = xp4[tid + it * 256];
        sum   += v[it].x + v[it].y + v[it].z + v[it].w;
        sumsq += v[it].x*v[it].x + v[it].y*v[it].y
               + v[it].z*v[it].z + v[it].w*v[it].w;
    }

    // ---- wave(64) butterfly reduce ----
    #pragma unroll
    for (int off = 32; off > 0; off >>= 1) {
        sum   += __shfl_down(sum,   off, 64);
        sumsq += __shfl_down(sumsq, off, 64);
    }
    __shared__ float s_sum[4], s_sq[4];
    __shared__ float s_ab[2];
    const int wave = tid >> 6;
    if ((tid & 63) == 0) { s_sum[wave] = sum; s_sq[wave] = sumsq; }
    __syncthreads();

    // ---- thread 0: finish reduce, run both MLPs, publish coefs ----
    if (tid == 0) {
        const float S = s_sum[0] + s_sum[1] + s_sum[2] + s_sum[3];
        const float Q = s_sq[0]  + s_sq[1]  + s_sq[2]  + s_sq[3];
        const float N = (float)HW;
        const float mean = S / N;
        const float var  = (Q - S * mean) / (N - 1.0f);   // ddof=1
        const float stdv = sqrtf(var + EPSV);

        float accm = bm2[0];
        #pragma unroll
        for (int h = 0; h < 16; ++h) {
            float hv = fmaf(wm1[h*2+0], mean, fmaf(wm1[h*2+1], stdv, bm1[h]));
            accm = fmaf(wm2[h], fmaxf(hv, 0.f), accm);
        }
        const float mw = 1.f / (1.f + expf(-accm));

        float accs = bs2[0];
        #pragma unroll
        for (int h = 0; h < 16; ++h) {
            float hv = fmaf(ws1[h*2+0], mean, fmaf(ws1[h*2+1], stdv, bs1[h]));
            accs = fmaf(ws2[h], fmaxf(hv, 0.f), accs);
        }
        const float sw = 1.f / (1.f + expf(-accs));

        // out = (x - m)*sw + m*mw = sw*x + m*(mw - sw)
        s_ab[0] = sw;
        s_ab[1] = mean * (mw - sw);
    }
    __syncthreads();

    // ---- apply from registers, write out ----
    const float a = s_ab[0];
    const float b = s_ab[1];
    #pragma unroll
    for (int it = 0; it < 4; ++it) {
        float4 o;
        o.x = fmaf(v[it].x, a, b);
        o.y = fmaf(v[it].y, a, b);
        o.z = fmaf(v[it].z, a, b);
        o.w = fmaf(v[it].w, a, b);
        op4[tid + it * 256] = o;
    }
}

extern "C" void kernel_launch(void* const* d_in, const int* in_sizes, int n_in,
                              void* d_out, int out_size, void* d_ws, size_t ws_size,
                              hipStream_t stream) {
    const float* x   = (const float*)d_in[0];
    const float* wm1 = (const float*)d_in[1];
    const float* bm1 = (const float*)d_in[2];
    const float* wm2 = (const float*)d_in[3];
    const float* bm2 = (const float*)d_in[4];
    const float* ws1 = (const float*)d_in[5];
    const float* bs1 = (const float*)d_in[6];
    const float* ws2 = (const float*)d_in[7];
    const float* bs2 = (const float*)d_in[8];
    float* out = (float*)d_out;

    cnsn_fused<<<NBC, 256, 0, stream>>>(x, wm1, bm1, wm2, bm2,
                                        ws1, bs1, ws2, bs2, out);
}

// Round 4
// 96.407 us; speedup vs baseline: 1.6639x; 1.0406x over previous
//
#include <hip/hip_runtime.h>
#include <math.h>

#define EPSV 1e-5f
#define HW   4096     // H*W = 64*64
#define NBC  16384    // B*C = 64*256
#define WPB  4        // waves per block (independent channels, no barriers)

typedef float vf4 __attribute__((ext_vector_type(4)));  // clang-native float4

// One wave (64 lanes) per channel: 4096 floats = 16 vf4/lane in registers.
// shfl_xor butterfly -> every lane holds full sum/sumsq; every lane computes
// the two tiny MLPs redundantly (uniform -> scalar-friendly). No LDS, no
// __syncthreads. Streaming loads/stores are nontemporal.
__global__ __launch_bounds__(256) void cnsn_fused_wave(
    const float* __restrict__ x,
    const float* __restrict__ wm1, const float* __restrict__ bm1,
    const float* __restrict__ wm2, const float* __restrict__ bm2,
    const float* __restrict__ ws1, const float* __restrict__ bs1,
    const float* __restrict__ ws2, const float* __restrict__ bs2,
    float* __restrict__ out)
{
    const int wave = threadIdx.x >> 6;
    const int lane = threadIdx.x & 63;
    const int bc   = blockIdx.x * WPB + wave;       // 0..NBC-1
    const size_t base = (size_t)bc * HW;
    const vf4* __restrict__ xp4 = (const vf4*)(x + base);
    vf4*       __restrict__ op4 = (vf4*)(out + base);

    // ---- load 16 x vf4 into registers, accumulate sum / sumsq ----
    vf4 v[16];
    float sum = 0.f, sumsq = 0.f;
    #pragma unroll
    for (int it = 0; it < 16; ++it) {
        v[it] = __builtin_nontemporal_load(&xp4[lane + it * 64]);
        sum   += v[it].x + v[it].y + v[it].z + v[it].w;
        sumsq += v[it].x*v[it].x + v[it].y*v[it].y
               + v[it].z*v[it].z + v[it].w*v[it].w;
    }

    // ---- 64-lane butterfly: every lane ends with the full totals ----
    #pragma unroll
    for (int off = 32; off > 0; off >>= 1) {
        sum   += __shfl_xor(sum,   off, 64);
        sumsq += __shfl_xor(sumsq, off, 64);
    }

    // ---- per-lane (uniform) stats + both MLPs ----
    const float N    = (float)HW;
    const float mean = sum / N;
    const float var  = (sumsq - sum * mean) / (N - 1.0f);   // ddof=1
    const float stdv = sqrtf(var + EPSV);

    float accm = bm2[0];
    #pragma unroll
    for (int h = 0; h < 16; ++h) {
        float hv = fmaf(wm1[h*2+0], mean, fmaf(wm1[h*2+1], stdv, bm1[h]));
        accm = fmaf(wm2[h], fmaxf(hv, 0.f), accm);
    }
    const float mw = 1.f / (1.f + expf(-accm));

    float accs = bs2[0];
    #pragma unroll
    for (int h = 0; h < 16; ++h) {
        float hv = fmaf(ws1[h*2+0], mean, fmaf(ws1[h*2+1], stdv, bs1[h]));
        accs = fmaf(ws2[h], fmaxf(hv, 0.f), accs);
    }
    const float sw = 1.f / (1.f + expf(-accs));

    // out = (x - m)*sw + m*mw = sw*x + m*(mw - sw)
    const float a = sw;
    const float b = mean * (mw - sw);

    // ---- apply from registers, nontemporal store ----
    #pragma unroll
    for (int it = 0; it < 16; ++it) {
        vf4 o;
        o.x = fmaf(v[it].x, a, b);
        o.y = fmaf(v[it].y, a, b);
        o.z = fmaf(v[it].z, a, b);
        o.w = fmaf(v[it].w, a, b);
        __builtin_nontemporal_store(o, &op4[lane + it * 64]);
    }
}

extern "C" void kernel_launch(void* const* d_in, const int* in_sizes, int n_in,
                              void* d_out, int out_size, void* d_ws, size_t ws_size,
                              hipStream_t stream) {
    const float* x   = (const float*)d_in[0];
    const float* wm1 = (const float*)d_in[1];
    const float* bm1 = (const float*)d_in[2];
    const float* wm2 = (const float*)d_in[3];
    const float* bm2 = (const float*)d_in[4];
    const float* ws1 = (const float*)d_in[5];
    const float* bs1 = (const float*)d_in[6];
    const float* ws2 = (const float*)d_in[7];
    const float* bs2 = (const float*)d_in[8];
    float* out = (float*)d_out;

    cnsn_fused_wave<<<NBC / WPB, 256, 0, stream>>>(x, wm1, bm1, wm2, bm2,
                                                   ws1, bs1, ws2, bs2, out);
}

// Round 5
// 84.018 us; speedup vs baseline: 1.9093x; 1.1475x over previous
//
#include <hip/hip_runtime.h>
#include <math.h>

#define EPSV 1e-5f
#define HW   4096     // H*W = 64*64
#define NBC  16384    // B*C = 64*256
#define WPB  4        // waves per block (independent channels, no barriers)

typedef float vf4 __attribute__((ext_vector_type(4)));  // clang-native float4

// One wave (64 lanes) per channel: 4096 floats = 16 vf4/lane in registers.
// shfl_xor butterfly -> every lane holds full sum/sumsq; every lane computes
// the two tiny MLPs redundantly (uniform -> scalar-friendly). No LDS, no
// __syncthreads. Loads are regular (read-once, nt hint suspected harmful);
// stores stay nontemporal (streaming, no-allocate).
__global__ __launch_bounds__(256) void cnsn_fused_wave(
    const float* __restrict__ x,
    const float* __restrict__ wm1, const float* __restrict__ bm1,
    const float* __restrict__ wm2, const float* __restrict__ bm2,
    const float* __restrict__ ws1, const float* __restrict__ bs1,
    const float* __restrict__ ws2, const float* __restrict__ bs2,
    float* __restrict__ out)
{
    const int wave = threadIdx.x >> 6;
    const int lane = threadIdx.x & 63;
    const int bc   = blockIdx.x * WPB + wave;       // 0..NBC-1
    const size_t base = (size_t)bc * HW;
    const vf4* __restrict__ xp4 = (const vf4*)(x + base);
    vf4*       __restrict__ op4 = (vf4*)(out + base);

    // ---- load 16 x vf4 into registers, accumulate sum / sumsq ----
    vf4 v[16];
    float sum = 0.f, sumsq = 0.f;
    #pragma unroll
    for (int it = 0; it < 16; ++it) {
        v[it] = xp4[lane + it * 64];               // plain load (A/B vs nt)
        sum   += v[it].x + v[it].y + v[it].z + v[it].w;
        sumsq += v[it].x*v[it].x + v[it].y*v[it].y
               + v[it].z*v[it].z + v[it].w*v[it].w;
    }

    // ---- 64-lane butterfly: every lane ends with the full totals ----
    #pragma unroll
    for (int off = 32; off > 0; off >>= 1) {
        sum   += __shfl_xor(sum,   off, 64);
        sumsq += __shfl_xor(sumsq, off, 64);
    }

    // ---- per-lane (uniform) stats + both MLPs ----
    const float N    = (float)HW;
    const float mean = sum / N;
    const float var  = (sumsq - sum * mean) / (N - 1.0f);   // ddof=1
    const float stdv = sqrtf(var + EPSV);

    float accm = bm2[0];
    #pragma unroll
    for (int h = 0; h < 16; ++h) {
        float hv = fmaf(wm1[h*2+0], mean, fmaf(wm1[h*2+1], stdv, bm1[h]));
        accm = fmaf(wm2[h], fmaxf(hv, 0.f), accm);
    }
    const float mw = 1.f / (1.f + expf(-accm));

    float accs = bs2[0];
    #pragma unroll
    for (int h = 0; h < 16; ++h) {
        float hv = fmaf(ws1[h*2+0], mean, fmaf(ws1[h*2+1], stdv, bs1[h]));
        accs = fmaf(ws2[h], fmaxf(hv, 0.f), accs);
    }
    const float sw = 1.f / (1.f + expf(-accs));

    // out = (x - m)*sw + m*mw = sw*x + m*(mw - sw)
    const float a = sw;
    const float b = mean * (mw - sw);

    // ---- apply from registers, nontemporal store ----
    #pragma unroll
    for (int it = 0; it < 16; ++it) {
        vf4 o;
        o.x = fmaf(v[it].x, a, b);
        o.y = fmaf(v[it].y, a, b);
        o.z = fmaf(v[it].z, a, b);
        o.w = fmaf(v[it].w, a, b);
        __builtin_nontemporal_store(o, &op4[lane + it * 64]);
    }
}

extern "C" void kernel_launch(void* const* d_in, const int* in_sizes, int n_in,
                              void* d_out, int out_size, void* d_ws, size_t ws_size,
                              hipStream_t stream) {
    const float* x   = (const float*)d_in[0];
    const float* wm1 = (const float*)d_in[1];
    const float* bm1 = (const float*)d_in[2];
    const float* wm2 = (const float*)d_in[3];
    const float* bm2 = (const float*)d_in[4];
    const float* ws1 = (const float*)d_in[5];
    const float* bs1 = (const float*)d_in[6];
    const float* ws2 = (const float*)d_in[7];
    const float* bs2 = (const float*)d_in[8];
    float* out = (float*)d_out;

    cnsn_fused_wave<<<NBC / WPB, 256, 0, stream>>>(x, wm1, bm1, wm2, bm2,
                                                   ws1, bs1, ws2, bs2, out);
}